// Round 6
// baseline (1011.466 us; speedup 1.0000x reference)
//
#include <hip/hip_runtime.h>
#include <hip/hip_bf16.h>

// Problem constants (fixed by setup_inputs)
#define B_ 8
#define N_ 16384
#define C_ 64
#define S_ 5

typedef float v4f __attribute__((ext_vector_type(4)));
typedef __bf16 v8bf __attribute__((ext_vector_type(8)));
typedef unsigned int v4u __attribute__((ext_vector_type(4)));

static __device__ __forceinline__ unsigned int pk2bf(float a, float b) {
    float2 f2; f2.x = a; f2.y = b;
    __hip_bfloat162 h2 = __float22bfloat162_rn(f2);
    unsigned int u; __builtin_memcpy(&u, &h2, 4);
    return u;
}
static __device__ __forceinline__ float bf2f(unsigned short s) {
    return __uint_as_float(((unsigned int)s) << 16);
}
static __device__ __forceinline__ float getv(const v4f* h, int e) {
    // e in [0,8): element from two v4f halves (constant-folded in unrolled code)
    return e < 4 ? h[0][e] : h[1][e - 4];
}

// ---------------------------------------------------------------------------
// ONE mega-kernel. Roles:
//  - every block: atomicAdd ticket; tickets 0..7 run FPS for batch=ticket
//    (dists in ws scratch), then sbg/ebb, then release per-batch flag
//    (agent scope). Deadlock-free: winners are by construction blocks that
//    are already executing; they depend on nothing.
//  - bid < 2048: fusion tile (b = bid>>8, n0 = (bid&255)*64). Staging, GEMM1
//    and slice 0 are FPS-independent; poll flag[b] (acquire + s_sleep) only
//    before slices 1..5. Weight A-frags built in-block from raw w1/w2 + BN.
//  - bid >= 2048: fg_xyz passthrough copy (96 blocks).
// MFMA layouts (HW-verified): A[m=lane&15][k=(lane>>4)*8+j];
// C/D: col=lane&15, row=(lane>>4)*4+reg.
// ---------------------------------------------------------------------------
#define PITCH 72 // shorts per LDS row: 2-way (free) bank aliasing on b64/b128

__global__ __launch_bounds__(256) void fusion_mega(
    const float* __restrict__ fg_xyz, const float* __restrict__ fg_feat,
    const float* __restrict__ bg_xyz, const float* __restrict__ bg_feat,
    const float* __restrict__ w1, const float* __restrict__ g1, const float* __restrict__ b1,
    const float* __restrict__ m1, const float* __restrict__ v1,
    const float* __restrict__ w2, const float* __restrict__ g2, const float* __restrict__ b2,
    const float* __restrict__ m2, const float* __restrict__ v2,
    float* __restrict__ out_xyz, float* __restrict__ out,
    float* __restrict__ ebbg, float* __restrict__ sbgg,
    int* __restrict__ ctl, float* __restrict__ distws) {
    __shared__ __align__(16) unsigned short Ft[64 * PITCH];     // 9.2 KB
    __shared__ __align__(16) unsigned short Ht[2][64 * PITCH];  // 18.4 KB (dbuf)
    __shared__ __align__(16) float cBb1[64];
    __shared__ __align__(16) float cBb2[64];
    __shared__ float sf[S_][64];
    __shared__ float s_best[4];
    __shared__ int s_bidx[4];
    __shared__ int s_last;
    __shared__ int s_idx[S_];
    __shared__ int s_ticket;

    const int t = threadIdx.x;
    const int bid = blockIdx.x;

    // ---- ticket: first 8 arriving blocks run FPS ----
    if (t == 0) s_ticket = atomicAdd(&ctl[0], 1);
    __syncthreads();
    const int tick = s_ticket;

    if (tick < B_) {
        // ================= FPS for batch = tick =================
        const float* p = bg_xyz + (size_t)tick * N_ * 3;
        float* dist = distws + (size_t)tick * N_;
        int last = 0;
        if (t == 0) s_idx[0] = 0;

        for (int step = 1; step < S_; ++step) {
            const float lx = p[last * 3 + 0];
            const float ly = p[last * 3 + 1];
            const float lz = p[last * 3 + 2];
            float best = -1.0f;
            int bidx = 0;
#pragma unroll 8
            for (int g = 0; g < 64; ++g) {
                const int i = g * 256 + t;
                float dx = p[i * 3 + 0] - lx;
                float dy = p[i * 3 + 1] - ly;
                float dz = p[i * 3 + 2] - lz;
                float d = dx * dx + dy * dy + dz * dz;
                float nd;
                if (step == 1) nd = d;            // ws is poisoned; no min on 1st pass
                else           nd = fminf(dist[i], d);
                dist[i] = nd;
                // strict >: keeps LOWEST index within thread (i ascending in g)
                if (nd > best) { best = nd; bidx = i; }
            }
            // wave(64) reduce; tie -> smaller index (jnp.argmax = first max)
#pragma unroll
            for (int off = 32; off > 0; off >>= 1) {
                float ob = __shfl_down(best, off, 64);
                int oi = __shfl_down(bidx, off, 64);
                if (ob > best || (ob == best && oi < bidx)) { best = ob; bidx = oi; }
            }
            if ((t & 63) == 0) { s_best[t >> 6] = best; s_bidx[t >> 6] = bidx; }
            __syncthreads();
            if (t == 0) {
                float bb = s_best[0];
                int bi = s_bidx[0];
#pragma unroll
                for (int w = 1; w < 4; ++w) {
                    if (s_best[w] > bb || (s_best[w] == bb && s_bidx[w] < bi)) {
                        bb = s_best[w];
                        bi = s_bidx[w];
                    }
                }
                s_last = bi;
                s_idx[step] = bi;
            }
            __syncthreads();
            last = s_last;
            __syncthreads(); // protect s_best before next step's overwrite
        }

        // ---- sbg gather + ebb = s1.*(W1b @ sbg) + bb1 ----
        for (int i = t; i < S_ * 64; i += 256) {
            const int j = i >> 6, c = i & 63;
            sf[j][c] = bg_feat[(size_t)tick * C_ * N_ + (size_t)c * N_ + s_idx[j]];
        }
        __syncthreads();
        for (int i = t; i < S_ * 64; i += 256) {
            const int j = i >> 6, o = i & 63;
            const float s1 = g1[o] * rsqrtf(v1[o] + 1e-5f);
            const float4* wr = (const float4*)&w1[o * 128 + 64];
            float acc = 0.f;
#pragma unroll
            for (int c4 = 0; c4 < 16; ++c4) {
                float4 wv = wr[c4];
                acc += wv.x * sf[j][c4 * 4 + 0] + wv.y * sf[j][c4 * 4 + 1] +
                       wv.z * sf[j][c4 * 4 + 2] + wv.w * sf[j][c4 * 4 + 3];
            }
            sbgg[(tick * S_ + j) * 64 + o] = sf[j][o];
            ebbg[(tick * S_ + j) * 64 + o] = s1 * acc + (b1[o] - m1[o] * s1);
        }
        __threadfence();   // make this thread's stores device-visible
        __syncthreads();   // all threads' fences done before the flag store
        if (t == 0)
            __hip_atomic_store(&ctl[1 + tick], 1, __ATOMIC_RELEASE,
                               __HIP_MEMORY_SCOPE_AGENT);
        __syncthreads();
    }

    // ================= role dispatch =================
    if (bid >= 2048) {
        // ---- fg_xyz copy: 96 blocks x 256 thr x 4 float4 = 1.5 MB ----
        const int base = (bid - 2048) * 1024 + t;
#pragma unroll
        for (int k = 0; k < 4; ++k)
            ((float4*)out_xyz)[base + k * 256] = ((const float4*)fg_xyz)[base + k * 256];
        return;
    }

    // ================= fusion tile =================
    const int b = bid >> 8;
    const int n0 = (bid & 255) * 64;
    const float* Fg = fg_feat + (size_t)b * C_ * N_ + n0;

    const int lane = t & 63;
    const int wv = t >> 6;     // wave id -> o-block (wave owns o rows [16wv,+16))
    const int o0 = wv * 16;
    const int m = lane & 15;   // A row / B col / D col
    const int q = lane >> 4;   // k-chunk / D row-group
    const int o4 = o0 + 4 * q; // this lane's 4-channel output group
    const int arow = o0 + m;

    // ---- stage F tile transposed (bf16) into Ft[n][c] ----
    {
        const int n = t & 63;
        const int cg = (t >> 6) * 16;
        float fr[16];
#pragma unroll
        for (int i = 0; i < 16; ++i) fr[i] = Fg[(size_t)(cg + i) * N_ + n];
        v4u w0, w1v;
#pragma unroll
        for (int i = 0; i < 8; ++i) {
            unsigned int pk = pk2bf(fr[2 * i], fr[2 * i + 1]);
            if (i < 4) w0[i] = pk; else w1v[i - 4] = pk;
        }
        *(v4u*)&Ft[n * PITCH + cg] = w0;
        *(v4u*)&Ft[n * PITCH + cg + 8] = w1v;
    }

    // ---- in-block weight A-frag build (rows arow, BN-folded, bf16) ----
    v8bf aWa[2], aWc[2], aW2[2];
    {
        const float s1 = g1[arow] * rsqrtf(v1[arow] + 1e-5f);
        const float s2 = g2[arow] * rsqrtf(v2[arow] + 1e-5f);
        const float* w1r = w1 + arow * 128;
        const float* w2r = w2 + arow * 64;
#pragma unroll
        for (int ks = 0; ks < 2; ++ks) {
            const int k0 = ks * 32 + q * 8;
            v4f wA[2], wB[2], w2v[2];
            wA[0] = *(const v4f*)&w1r[k0];
            wA[1] = *(const v4f*)&w1r[k0 + 4];
            wB[0] = *(const v4f*)&w1r[64 + k0];
            wB[1] = *(const v4f*)&w1r[64 + k0 + 4];
            w2v[0] = *(const v4f*)&w2r[k0];
            w2v[1] = *(const v4f*)&w2r[k0 + 4];
            unsigned int ua[4], uc[4], u2[4];
#pragma unroll
            for (int d = 0; d < 4; ++d) {
                float a0 = getv(wA, 2 * d), a1 = getv(wA, 2 * d + 1);
                float b0 = getv(wB, 2 * d), b1v = getv(wB, 2 * d + 1);
                float c0 = getv(w2v, 2 * d), c1 = getv(w2v, 2 * d + 1);
                ua[d] = pk2bf(s1 * a0, s1 * a1);
                uc[d] = pk2bf(s1 * (a0 + b0), s1 * (a1 + b1v));
                u2[d] = pk2bf(s2 * c0, s2 * c1);
            }
            __builtin_memcpy(&aWa[ks], ua, 16);
            __builtin_memcpy(&aWc[ks], uc, 16);
            __builtin_memcpy(&aW2[ks], u2, 16);
        }
    }

    // ---- bb1/bb2 into LDS (threads 0..63) ----
    if (t < 64) {
        const float s1 = g1[t] * rsqrtf(v1[t] + 1e-5f);
        const float s2 = g2[t] * rsqrtf(v2[t] + 1e-5f);
        cBb1[t] = b1[t] - m1[t] * s1;
        cBb2[t] = b2[t] - m2[t] * s2;
    }

    __syncthreads(); // Ft + cBb ready

    // B-frags of F: this wave needs all 64 columns (4 nb blocks)
    v8bf bF[4][2];
#pragma unroll
    for (int nb = 0; nb < 4; ++nb)
#pragma unroll
        for (int ks = 0; ks < 2; ++ks)
            bF[nb][ks] = *(const v8bf*)&Ft[(nb * 16 + m) * PITCH + ks * 32 + q * 8];

    // GEMM1: U = Wa'.F (slices>=1), U0 = Wc'.F (slice 0)
    v4f U[4], U0[4];
#pragma unroll
    for (int nb = 0; nb < 4; ++nb) {
        v4f z = {0.f, 0.f, 0.f, 0.f};
        z = __builtin_amdgcn_mfma_f32_16x16x32_bf16(aWa[0], bF[nb][0], z, 0, 0, 0);
        U[nb] = __builtin_amdgcn_mfma_f32_16x16x32_bf16(aWa[1], bF[nb][1], z, 0, 0, 0);
        v4f z2 = {0.f, 0.f, 0.f, 0.f};
        z2 = __builtin_amdgcn_mfma_f32_16x16x32_bf16(aWc[0], bF[nb][0], z2, 0, 0, 0);
        U0[nb] = __builtin_amdgcn_mfma_f32_16x16x32_bf16(aWc[1], bF[nb][1], z2, 0, 0, 0);
    }

    v4f acc[4];
#pragma unroll
    for (int nb = 0; nb < 4; ++nb) acc[nb] = (v4f){0.f, 0.f, 0.f, 0.f};

    const v4f bb2r = *(const v4f*)&cBb2[o4];

#pragma unroll
    for (int s = 0; s < 6; ++s) {
        if (s == 1) {
            // FPS constants needed from here on: acquire-poll this batch's flag
            while (__hip_atomic_load(&ctl[1 + b], __ATOMIC_ACQUIRE,
                                     __HIP_MEMORY_SCOPE_AGENT) == 0)
                __builtin_amdgcn_s_sleep(8);
        }
        unsigned short* h = &Ht[s & 1][0]; // slice-parity double buffer
        v4f cv = (s == 0) ? *(const v4f*)&cBb1[o4]
                          : *(const v4f*)&ebbg[(b * S_ + (s - 1)) * 64 + o4];
        // form H (C-layout, rows o4..o4+3) -> Ht[n][o] transposed
#pragma unroll
        for (int nb = 0; nb < 4; ++nb) {
            v4f u = (s == 0) ? U0[nb] : U[nb];
            unsigned int lo = pk2bf(fmaxf(u[0] + cv[0], 0.f), fmaxf(u[1] + cv[1], 0.f));
            unsigned int hi = pk2bf(fmaxf(u[2] + cv[2], 0.f), fmaxf(u[3] + cv[3], 0.f));
            unsigned long long vv = (unsigned long long)lo | ((unsigned long long)hi << 32);
            *(unsigned long long*)&h[(nb * 16 + m) * PITCH + o4] = vv;
        }
        __syncthreads(); // Ht[s&1] ready

        // GEMM2 p = W2'.H + epilogue: acc += relu(p + bb2) * multiplier
        v4f sb;
        if (s > 0) sb = *(const v4f*)&sbgg[(b * S_ + (s - 1)) * 64 + o4];
#pragma unroll
        for (int nb = 0; nb < 4; ++nb) {
            v8bf h0 = *(const v8bf*)&h[(nb * 16 + m) * PITCH + q * 8];
            v8bf h1 = *(const v8bf*)&h[(nb * 16 + m) * PITCH + 32 + q * 8];
            v4f z = {0.f, 0.f, 0.f, 0.f};
            z = __builtin_amdgcn_mfma_f32_16x16x32_bf16(aW2[0], h0, z, 0, 0, 0);
            v4f p4 = __builtin_amdgcn_mfma_f32_16x16x32_bf16(aW2[1], h1, z, 0, 0, 0);

            if (s == 0) {
                unsigned long long fv =
                    *(const unsigned long long*)&Ft[(nb * 16 + m) * PITCH + o4];
#pragma unroll
                for (int r = 0; r < 4; ++r) {
                    float wgt = fmaxf(p4[r] + bb2r[r], 0.f);
                    acc[nb][r] += wgt * bf2f((unsigned short)(fv >> (16 * r)));
                }
            } else {
#pragma unroll
                for (int r = 0; r < 4; ++r) {
                    float wgt = fmaxf(p4[r] + bb2r[r], 0.f);
                    acc[nb][r] += wgt * sb[r];
                }
            }
        }
    }

    // store: out[b][o][n], o = o4+r, n = n0 + nb*16 + m
    const size_t outb = (size_t)b * C_ * N_ + n0;
#pragma unroll
    for (int nb = 0; nb < 4; ++nb)
#pragma unroll
        for (int r = 0; r < 4; ++r)
            out[outb + (size_t)(o4 + r) * N_ + (nb * 16 + m)] = acc[nb][r];
}

// ---------------------------------------------------------------------------
extern "C" void kernel_launch(void* const* d_in, const int* in_sizes, int n_in,
                              void* d_out, int out_size, void* d_ws, size_t ws_size,
                              hipStream_t stream) {
    const float* fg_xyz = (const float*)d_in[0];
    const float* fg_feat = (const float*)d_in[1];
    const float* bg_xyz = (const float*)d_in[2];
    const float* bg_feat = (const float*)d_in[3];
    const float* w1 = (const float*)d_in[4];
    const float* g1 = (const float*)d_in[5];
    const float* b1 = (const float*)d_in[6];
    const float* m1 = (const float*)d_in[7];
    const float* v1 = (const float*)d_in[8];
    const float* w2 = (const float*)d_in[9];
    const float* g2 = (const float*)d_in[10];
    const float* b2 = (const float*)d_in[11];
    const float* m2 = (const float*)d_in[12];
    const float* v2 = (const float*)d_in[13];

    // workspace layout (float units)
    float* ws = (float*)d_ws;
    float* ebb = ws;                        // 2560
    float* sbg = ebb + 2560;                // 2560
    int* ctl = (int*)(ws + 5120);           // [0]=ticket, [1..8]=flags (64 B)
    float* distws = ws + 8192;              // 8 x 16384 FPS dists

    float* out_feats = (float*)d_out + (size_t)B_ * N_ * 3;

    // node 1: clear ticket + flags (ws is poisoned 0xAA every launch)
    hipMemsetAsync(ctl, 0, 64, stream);
    // node 2: everything
    fusion_mega<<<2144, 256, 0, stream>>>(
        fg_xyz, fg_feat, bg_xyz, bg_feat,
        w1, g1, b1, m1, v1, w2, g2, b2, m2, v2,
        (float*)d_out, out_feats, ebb, sbg, ctl, distws);
}

// Round 7
// 168.585 us; speedup vs baseline: 5.9998x; 5.9998x over previous
//
#include <hip/hip_runtime.h>
#include <hip/hip_bf16.h>

// Problem constants (fixed by setup_inputs)
#define B_ 8
#define N_ 16384
#define C_ 64
#define S_ 5

typedef float v4f __attribute__((ext_vector_type(4)));
typedef __bf16 v8bf __attribute__((ext_vector_type(8)));
typedef unsigned int v4u __attribute__((ext_vector_type(4)));

static __device__ __forceinline__ unsigned int pk2bf(float a, float b) {
    float2 f2; f2.x = a; f2.y = b;
    __hip_bfloat162 h2 = __float22bfloat162_rn(f2);
    unsigned int u; __builtin_memcpy(&u, &h2, 4);
    return u;
}
static __device__ __forceinline__ float bf2f(unsigned short s) {
    return __uint_as_float(((unsigned int)s) << 16);
}
static __device__ __forceinline__ float getv(const v4f* h, int e) {
    return e < 4 ? h[0][e] : h[1][e - 4];
}

// ---------------------------------------------------------------------------
// Kernel 1: FPS only (8 blocks x 1024 thr; R5-verbatim) + sbg/ebb build.
// Stream-ordered producer for fusion's slices 1..5. NO cross-block signaling
// (R6 lesson: spin-wait on gfx950 can stall ~ms on stale lines).
// ---------------------------------------------------------------------------
__global__ __launch_bounds__(1024) void fps_sbg(
    const float* __restrict__ bg_xyz, const float* __restrict__ bg_feat,
    const float* __restrict__ w1, const float* __restrict__ g1,
    const float* __restrict__ b1, const float* __restrict__ m1,
    const float* __restrict__ v1,
    float* __restrict__ sbg, float* __restrict__ ebb) {
    const int b = blockIdx.x;
    const int t = threadIdx.x;
    const float* p = bg_xyz + (size_t)b * N_ * 3;

    float px[16], py[16], pz[16], dist[16];
    {
        const float4* pv = (const float4*)p + t * 12; // pts t*16 .. t*16+15
#pragma unroll
        for (int g = 0; g < 4; ++g) {
            float4 a = pv[g * 3 + 0];
            float4 bq = pv[g * 3 + 1];
            float4 c = pv[g * 3 + 2];
            px[g * 4 + 0] = a.x;  py[g * 4 + 0] = a.y;  pz[g * 4 + 0] = a.z;
            px[g * 4 + 1] = a.w;  py[g * 4 + 1] = bq.x; pz[g * 4 + 1] = bq.y;
            px[g * 4 + 2] = bq.z; py[g * 4 + 2] = bq.w; pz[g * 4 + 2] = c.x;
            px[g * 4 + 3] = c.y;  py[g * 4 + 3] = c.z;  pz[g * 4 + 3] = c.w;
            dist[g * 4 + 0] = 1e10f; dist[g * 4 + 1] = 1e10f;
            dist[g * 4 + 2] = 1e10f; dist[g * 4 + 3] = 1e10f;
        }
    }

    __shared__ float s_best[16];
    __shared__ int s_bidx[16];
    __shared__ int s_last;
    __shared__ int s_idx[S_];
    __shared__ float sf[S_][64];
    int last = 0;
    if (t == 0) s_idx[0] = 0;

    for (int step = 1; step < S_; ++step) {
        const float lx = p[last * 3 + 0];
        const float ly = p[last * 3 + 1];
        const float lz = p[last * 3 + 2];
        float best = -1.0f;
        int bidx = 0;
#pragma unroll
        for (int k = 0; k < 16; ++k) {
            float dx = px[k] - lx, dy = py[k] - ly, dz = pz[k] - lz;
            float d = dx * dx + dy * dy + dz * dz;
            float nd = fminf(dist[k], d);
            dist[k] = nd;
            // strict >: keeps the LOWEST index within this thread (k ascending)
            if (nd > best) { best = nd; bidx = t * 16 + k; }
        }
        // wave(64) reduce; tie -> smaller index (jnp.argmax = first max)
#pragma unroll
        for (int off = 32; off > 0; off >>= 1) {
            float ob = __shfl_down(best, off, 64);
            int oi = __shfl_down(bidx, off, 64);
            if (ob > best || (ob == best && oi < bidx)) { best = ob; bidx = oi; }
        }
        if ((t & 63) == 0) { s_best[t >> 6] = best; s_bidx[t >> 6] = bidx; }
        __syncthreads();
        if (t == 0) {
            float bb = s_best[0];
            int bi = s_bidx[0];
#pragma unroll
            for (int w = 1; w < 16; ++w) {
                if (s_best[w] > bb || (s_best[w] == bb && s_bidx[w] < bi)) {
                    bb = s_best[w];
                    bi = s_bidx[w];
                }
            }
            s_last = bi;
            s_idx[step] = bi;
        }
        __syncthreads();
        last = s_last;
        __syncthreads(); // protect s_best before next step's overwrite
    }

    // ---- sbg gather + ebb = s1.*(W1b @ sbg) + bb1 ----
    if (t < S_ * 64) {
        const int j = t >> 6, c = t & 63;
        sf[j][c] = bg_feat[(size_t)b * C_ * N_ + (size_t)c * N_ + s_idx[j]];
    }
    __syncthreads();
    if (t < S_ * 64) {
        const int j = t >> 6, o = t & 63;
        const float s1 = g1[o] * rsqrtf(v1[o] + 1e-5f);
        const float4* wr = (const float4*)&w1[o * 128 + 64];
        float acc = 0.f;
#pragma unroll
        for (int c4 = 0; c4 < 16; ++c4) {
            float4 wv = wr[c4];
            acc += wv.x * sf[j][c4 * 4 + 0] + wv.y * sf[j][c4 * 4 + 1] +
                   wv.z * sf[j][c4 * 4 + 2] + wv.w * sf[j][c4 * 4 + 3];
        }
        sbg[(b * S_ + j) * 64 + o] = sf[j][o];
        ebb[(b * S_ + j) * 64 + o] = s1 * acc + (b1[o] - m1[o] * s1);
    }
}

// ---------------------------------------------------------------------------
// Kernel 2: fusion (R5 core) + 2-tile register prefetch + in-block weight
// build + xyz copy blocks.
//   bid < 1024 : fusion, b = bid>>7, tiles nx=bid&127 and nx+128.
//   bid >= 1024: fg_xyz passthrough copy (96 blocks).
// R4's 2-tile prefetch failed ONLY from the __launch_bounds__ VGPR cap
// (115 MB spill traffic); no cap here. Weight A-frags built from raw
// w1/w2+BN in-block (R6-proven, VGPR 84 there).
// MFMA layouts (HW-verified): A[m=lane&15][k=(lane>>4)*8+j];
// C/D: col=lane&15, row=(lane>>4)*4+reg.
// ---------------------------------------------------------------------------
#define PITCH 72 // shorts per LDS row: 2-way (free) bank aliasing on b64/b128

__global__ __launch_bounds__(256) void fusion_main(
    const float* __restrict__ fg_xyz, const float* __restrict__ fg_feat,
    const float* __restrict__ w1, const float* __restrict__ g1,
    const float* __restrict__ b1, const float* __restrict__ m1,
    const float* __restrict__ v1,
    const float* __restrict__ w2, const float* __restrict__ g2,
    const float* __restrict__ b2, const float* __restrict__ m2,
    const float* __restrict__ v2,
    const float* __restrict__ ebbg, const float* __restrict__ sbgg,
    float* __restrict__ out_xyz, float* __restrict__ out) {
    __shared__ __align__(16) unsigned short Ft[2][64 * PITCH];  // 18.4 KB
    __shared__ __align__(16) unsigned short Ht[2][64 * PITCH];  // 18.4 KB
    __shared__ __align__(16) float cEbb[S_ * 64];
    __shared__ __align__(16) float cSbg[S_ * 64];
    __shared__ __align__(16) float cBb1[64];
    __shared__ __align__(16) float cBb2[64];

    const int t = threadIdx.x;
    const int bid = blockIdx.x;

    if (bid >= 1024) { // ---- fg_xyz copy: 96 blocks x 256 thr x 4 float4 ----
        const int base = (bid - 1024) * 1024 + t;
#pragma unroll
        for (int k = 0; k < 4; ++k)
            ((float4*)out_xyz)[base + k * 256] = ((const float4*)fg_xyz)[base + k * 256];
        return;
    }

    const int b = bid >> 7;
    const int nx = bid & 127;
    const float* Fbase = fg_feat + (size_t)b * C_ * N_;
    const size_t outb = (size_t)b * C_ * N_;

    const int lane = t & 63;
    const int wv = t >> 6;     // wave id -> o-block (wave owns o rows [16wv,+16))
    const int o0 = wv * 16;
    const int m = lane & 15;   // A row / B col / D col
    const int q = lane >> 4;   // k-chunk / D row-group
    const int o4 = o0 + 4 * q; // this lane's 4-channel output group
    const int arow = o0 + m;

    // staging geometry: thread t -> column sn, c rows [cg, cg+16)
    const int sn = t & 63;
    const int cg = (t >> 6) * 16;

    // ---- stage tile0 (bf16, transposed into Ft[0][n][c]) ----
    {
        const float* Fg = Fbase + (size_t)nx * 64 + sn;
        float fr[16];
#pragma unroll
        for (int i = 0; i < 16; ++i) fr[i] = Fg[(size_t)(cg + i) * N_];
        v4u w0, w1v;
#pragma unroll
        for (int i = 0; i < 8; ++i) {
            unsigned int pk = pk2bf(fr[2 * i], fr[2 * i + 1]);
            if (i < 4) w0[i] = pk; else w1v[i - 4] = pk;
        }
        *(v4u*)&Ft[0][sn * PITCH + cg] = w0;
        *(v4u*)&Ft[0][sn * PITCH + cg + 8] = w1v;
    }

    // ---- in-block weight A-frag build (row arow, BN-folded, bf16) ----
    v8bf aWa[2], aWc[2], aW2[2];
    {
        const float s1 = g1[arow] * rsqrtf(v1[arow] + 1e-5f);
        const float s2 = g2[arow] * rsqrtf(v2[arow] + 1e-5f);
        const float* w1r = w1 + arow * 128;
        const float* w2r = w2 + arow * 64;
#pragma unroll
        for (int ks = 0; ks < 2; ++ks) {
            const int k0 = ks * 32 + q * 8;
            v4f wA[2], wB[2], w2v[2];
            wA[0] = *(const v4f*)&w1r[k0];
            wA[1] = *(const v4f*)&w1r[k0 + 4];
            wB[0] = *(const v4f*)&w1r[64 + k0];
            wB[1] = *(const v4f*)&w1r[64 + k0 + 4];
            w2v[0] = *(const v4f*)&w2r[k0];
            w2v[1] = *(const v4f*)&w2r[k0 + 4];
            unsigned int ua[4], uc[4], u2[4];
#pragma unroll
            for (int d = 0; d < 4; ++d) {
                float a0 = getv(wA, 2 * d), a1 = getv(wA, 2 * d + 1);
                float b0 = getv(wB, 2 * d), b1v = getv(wB, 2 * d + 1);
                float c0 = getv(w2v, 2 * d), c1 = getv(w2v, 2 * d + 1);
                ua[d] = pk2bf(s1 * a0, s1 * a1);
                uc[d] = pk2bf(s1 * (a0 + b0), s1 * (a1 + b1v));
                u2[d] = pk2bf(s2 * c0, s2 * c1);
            }
            __builtin_memcpy(&aWa[ks], ua, 16);
            __builtin_memcpy(&aWc[ks], uc, 16);
            __builtin_memcpy(&aW2[ks], u2, 16);
        }
    }

    // ---- constants into LDS ----
    for (int i = t; i < S_ * 64; i += 256) {
        cEbb[i] = ebbg[b * (S_ * 64) + i];
        cSbg[i] = sbgg[b * (S_ * 64) + i];
    }
    if (t < 64) {
        const float s1 = g1[t] * rsqrtf(v1[t] + 1e-5f);
        const float s2 = g2[t] * rsqrtf(v2[t] + 1e-5f);
        cBb1[t] = b1[t] - m1[t] * s1;
        cBb2[t] = b2[t] - m2[t] * s2;
    }

    __syncthreads(); // Ft[0] + constants ready

    // ---- issue tile1's global loads NOW (in flight under tile0 compute) ----
    float fr1[16];
    {
        const float* Fg1 = Fbase + (size_t)(nx + 128) * 64 + sn;
#pragma unroll
        for (int i = 0; i < 16; ++i) fr1[i] = Fg1[(size_t)(cg + i) * N_];
    }

    const v4f bb2r = *(const v4f*)&cBb2[o4];

    // ---- per-tile compute: R5 core (6 slices, Ht parity dbuf) ----
    auto tile_compute = [&](const unsigned short* F, size_t obase) {
        v8bf bF[4][2];
#pragma unroll
        for (int nb = 0; nb < 4; ++nb)
#pragma unroll
            for (int ks = 0; ks < 2; ++ks)
                bF[nb][ks] = *(const v8bf*)&F[(nb * 16 + m) * PITCH + ks * 32 + q * 8];

        v4f U[4], U0[4];
#pragma unroll
        for (int nb = 0; nb < 4; ++nb) {
            v4f z = {0.f, 0.f, 0.f, 0.f};
            z = __builtin_amdgcn_mfma_f32_16x16x32_bf16(aWa[0], bF[nb][0], z, 0, 0, 0);
            U[nb] = __builtin_amdgcn_mfma_f32_16x16x32_bf16(aWa[1], bF[nb][1], z, 0, 0, 0);
            v4f z2 = {0.f, 0.f, 0.f, 0.f};
            z2 = __builtin_amdgcn_mfma_f32_16x16x32_bf16(aWc[0], bF[nb][0], z2, 0, 0, 0);
            U0[nb] = __builtin_amdgcn_mfma_f32_16x16x32_bf16(aWc[1], bF[nb][1], z2, 0, 0, 0);
        }

        v4f acc[4];
#pragma unroll
        for (int nb = 0; nb < 4; ++nb) acc[nb] = (v4f){0.f, 0.f, 0.f, 0.f};

#pragma unroll
        for (int s = 0; s < 6; ++s) {
            unsigned short* h = &Ht[s & 1][0]; // slice-parity double buffer
            v4f cv = (s == 0) ? *(const v4f*)&cBb1[o4]
                              : *(const v4f*)&cEbb[(s - 1) * 64 + o4];
#pragma unroll
            for (int nb = 0; nb < 4; ++nb) {
                v4f u = (s == 0) ? U0[nb] : U[nb];
                unsigned int lo = pk2bf(fmaxf(u[0] + cv[0], 0.f), fmaxf(u[1] + cv[1], 0.f));
                unsigned int hi = pk2bf(fmaxf(u[2] + cv[2], 0.f), fmaxf(u[3] + cv[3], 0.f));
                unsigned long long vv = (unsigned long long)lo | ((unsigned long long)hi << 32);
                *(unsigned long long*)&h[(nb * 16 + m) * PITCH + o4] = vv;
            }
            __syncthreads(); // Ht[s&1] ready

            v4f sb;
            if (s > 0) sb = *(const v4f*)&cSbg[(s - 1) * 64 + o4];
#pragma unroll
            for (int nb = 0; nb < 4; ++nb) {
                v8bf h0 = *(const v8bf*)&h[(nb * 16 + m) * PITCH + q * 8];
                v8bf h1 = *(const v8bf*)&h[(nb * 16 + m) * PITCH + 32 + q * 8];
                v4f z = {0.f, 0.f, 0.f, 0.f};
                z = __builtin_amdgcn_mfma_f32_16x16x32_bf16(aW2[0], h0, z, 0, 0, 0);
                v4f p4 = __builtin_amdgcn_mfma_f32_16x16x32_bf16(aW2[1], h1, z, 0, 0, 0);

                if (s == 0) {
                    unsigned long long fv =
                        *(const unsigned long long*)&F[(nb * 16 + m) * PITCH + o4];
#pragma unroll
                    for (int r = 0; r < 4; ++r) {
                        float wgt = fmaxf(p4[r] + bb2r[r], 0.f);
                        acc[nb][r] += wgt * bf2f((unsigned short)(fv >> (16 * r)));
                    }
                } else {
#pragma unroll
                    for (int r = 0; r < 4; ++r) {
                        float wgt = fmaxf(p4[r] + bb2r[r], 0.f);
                        acc[nb][r] += wgt * sb[r];
                    }
                }
            }
        }

#pragma unroll
        for (int nb = 0; nb < 4; ++nb)
#pragma unroll
            for (int r = 0; r < 4; ++r)
                out[obase + (size_t)(o4 + r) * N_ + (nb * 16 + m)] = acc[nb][r];
    };

    // tile 0
    tile_compute(&Ft[0][0], outb + (size_t)nx * 64);

    // pack prefetched tile1 into Ft[1]
    {
        v4u w0, w1v;
#pragma unroll
        for (int i = 0; i < 8; ++i) {
            unsigned int pk = pk2bf(fr1[2 * i], fr1[2 * i + 1]);
            if (i < 4) w0[i] = pk; else w1v[i - 4] = pk;
        }
        *(v4u*)&Ft[1][sn * PITCH + cg] = w0;
        *(v4u*)&Ft[1][sn * PITCH + cg + 8] = w1v;
    }
    __syncthreads(); // Ft[1] ready (also fences tile0's Ht usage)

    // tile 1
    tile_compute(&Ft[1][0], outb + (size_t)(nx + 128) * 64);
}

// ---------------------------------------------------------------------------
extern "C" void kernel_launch(void* const* d_in, const int* in_sizes, int n_in,
                              void* d_out, int out_size, void* d_ws, size_t ws_size,
                              hipStream_t stream) {
    const float* fg_xyz = (const float*)d_in[0];
    const float* fg_feat = (const float*)d_in[1];
    const float* bg_xyz = (const float*)d_in[2];
    const float* bg_feat = (const float*)d_in[3];
    const float* w1 = (const float*)d_in[4];
    const float* g1 = (const float*)d_in[5];
    const float* b1 = (const float*)d_in[6];
    const float* m1 = (const float*)d_in[7];
    const float* v1 = (const float*)d_in[8];
    const float* w2 = (const float*)d_in[9];
    const float* g2 = (const float*)d_in[10];
    const float* b2 = (const float*)d_in[11];
    const float* m2 = (const float*)d_in[12];
    const float* v2 = (const float*)d_in[13];

    // workspace layout (float units)
    float* ws = (float*)d_ws;
    float* ebb = ws;                        // 2560
    float* sbg = ebb + 2560;                // 2560

    float* out_feats = (float*)d_out + (size_t)B_ * N_ * 3;

    // node 1: FPS + sampled-bg constants (8 blocks; minimal serial prefix)
    fps_sbg<<<B_, 1024, 0, stream>>>(bg_xyz, bg_feat, w1, g1, b1, m1, v1,
                                     sbg, ebb);
    // node 2: fusion (1024 blocks x 2 tiles, reg-prefetch) + xyz copy (96)
    fusion_main<<<1120, 256, 0, stream>>>(
        fg_xyz, fg_feat, w1, g1, b1, m1, v1, w2, g2, b2, m2, v2,
        ebb, sbg, (float*)d_out, out_feats);
}